// Round 15
// baseline (265.584 us; speedup 1.0000x reference)
//
#include <hip/hip_runtime.h>
#include <math.h>

#define HD 8192
#define ID 4096
#define KSEL 409           // int(8192 * 0.05)
#define LR 0.001f

typedef float f4 __attribute__((ext_vector_type(4)));
typedef float f2 __attribute__((ext_vector_type(2)));

// workspace layout (float indices)
#define WS_H     0                       // 8192 f32: h = relu(x@W^T + b)
#define WS_HS    8192                    // 8192 f32: h_sparse dense
#define WS_IDX   16384                   // 8192 i32: compacted nonzero indices
#define WS_VAL   24576                   // 8192 f32: compacted values
#define WS_SCAL  32768                   // [0]=kth, [1]=inv_norm, [2](int)=n
#define WS_YPART 32832                   // 16*8192 f32 partials
#define WS_SSQ   (32832 + 16*8192)       // 2048 doubles (byte off 655616, 8-aligned)
#define WS_FPART (WS_SSQ + 4096)         // 128 doubles: 32 blocks x {dy,sh2,l0,l1}

// ---------- K1: h = relu(x @ W_enc^T + b), pure W stream ----------
__global__ __launch_bounds__(256) void k_enc(const float* __restrict__ x,
                                             const float* __restrict__ W,
                                             const float* __restrict__ b,
                                             float* __restrict__ ws) {
    __shared__ f4 sx[ID / 4];
    int tid = threadIdx.x;
    const f4* x4 = (const f4*)x;
    for (int k = tid; k < ID / 4; k += 256) sx[k] = x4[k];
    __syncthreads();
    int wave = tid >> 6, lane = tid & 63;
    int row = blockIdx.x * 4 + wave;
    const f4* w4 = (const f4*)(W + (size_t)row * ID);
    float acc = 0.f;
#pragma unroll
    for (int k = 0; k < 16; ++k) {
        f4 a  = w4[lane + 64 * k];
        f4 xv = sx[lane + 64 * k];
        acc += a.x * xv.x + a.y * xv.y + a.z * xv.z + a.w * xv.w;
    }
#pragma unroll
    for (int off = 32; off; off >>= 1) acc += __shfl_xor(acc, off, 64);
    if (lane == 0) {
        float h = acc + b[row];
        ws[WS_H + row] = h > 0.f ? h : 0.f;
    }
}

// ---------- K2 fused: blocks [0,2048) ssq(S) stream; block 2048 topk ----------
__global__ __launch_bounds__(256) void k_topkssq(const float* __restrict__ S,
                                                 float* __restrict__ ws) {
    int tid = threadIdx.x;
    if (blockIdx.x < 2048) {
        const f4* S4 = (const f4*)S;
        int gid = blockIdx.x * 256 + tid;
        double acc = 0.0;
        const int total4 = HD * HD / 4;  // 16777216
        for (int i = gid; i < total4; i += 2048 * 256) {
            f4 v = S4[i];  // warms L3 with S (forward stream)
            acc += (double)(v.x * v.x + v.y * v.y) + (double)(v.z * v.z + v.w * v.w);
        }
        __shared__ double sd[256];
        sd[tid] = acc;
        __syncthreads();
        for (int s = 128; s; s >>= 1) {
            if (tid < s) sd[tid] += sd[tid + s];
            __syncthreads();
        }
        if (tid == 0) ((double*)(ws + WS_SSQ))[blockIdx.x] = sd[0];
        return;
    }
    // ---- block 2048: exact top-K threshold + compaction (runs in parallel) ----
    float v[32];
    const f4* h4 = (const f4*)(ws + WS_H);
#pragma unroll
    for (int k = 0; k < 8; ++k) {
        f4 t = h4[tid * 8 + k];
        v[4 * k + 0] = t.x; v[4 * k + 1] = t.y; v[4 * k + 2] = t.z; v[4 * k + 3] = t.w;
    }
    __shared__ int sred[4];
    __shared__ int wsum[4];
    // h >= 0 (relu) -> float order == uint bit order. Find largest u with
    // count(h >= u) >= K: u is exactly the Kth-largest value.
    unsigned lo = 0u, hi = 0x7F800000u;
    while (hi - lo > 1u) {
        unsigned mid = (lo + hi) >> 1;
        float t = __uint_as_float(mid);
        int c = 0;
#pragma unroll
        for (int k = 0; k < 32; ++k) c += (v[k] >= t) ? 1 : 0;
#pragma unroll
        for (int off = 32; off; off >>= 1) c += __shfl_xor(c, off, 64);
        if ((tid & 63) == 0) sred[tid >> 6] = c;
        __syncthreads();
        int cnt = sred[0] + sred[1] + sred[2] + sred[3];
        __syncthreads();
        if (cnt >= KSEL) lo = mid; else hi = mid;
    }
    float kth = __uint_as_float(lo);

    int cnt_t = 0;
    f4* hs4 = (f4*)(ws + WS_HS);
#pragma unroll
    for (int k = 0; k < 8; ++k) {
        f4 o;
        o.x = (v[4 * k + 0] >= kth) ? v[4 * k + 0] : 0.f;
        o.y = (v[4 * k + 1] >= kth) ? v[4 * k + 1] : 0.f;
        o.z = (v[4 * k + 2] >= kth) ? v[4 * k + 2] : 0.f;
        o.w = (v[4 * k + 3] >= kth) ? v[4 * k + 3] : 0.f;
        hs4[tid * 8 + k] = o;
    }
#pragma unroll
    for (int k = 0; k < 32; ++k) cnt_t += ((v[k] >= kth) && (v[k] > 0.f)) ? 1 : 0;

    int c = cnt_t;
#pragma unroll
    for (int off = 1; off < 64; off <<= 1) {
        int y = __shfl_up(c, off, 64);
        if ((tid & 63) >= off) c += y;
    }
    if ((tid & 63) == 63) wsum[tid >> 6] = c;
    __syncthreads();
    int base = 0;
    for (int w = 0; w < (tid >> 6); ++w) base += wsum[w];
    int p = base + c - cnt_t;

    int* idx = ((int*)ws) + WS_IDX;
#pragma unroll
    for (int k = 0; k < 32; ++k) {
        float val = v[k];
        if ((val >= kth) && (val > 0.f)) {
            idx[p] = tid * 32 + k;
            ws[WS_VAL + p] = val;
            ++p;
        }
    }
    if (tid == 0) {
        ws[WS_SCAL + 0] = kth;
        ((int*)ws)[WS_SCAL + 2] = wsum[0] + wsum[1] + wsum[2] + wsum[3];
    }
}

// ---------- K3: y_partial = h_sparse @ S (rows L3-hot from ssq) ----------
__global__ __launch_bounds__(256) void k_ymv(const float* __restrict__ S,
                                             float* __restrict__ ws) {
    __shared__ int   sidx[2048];
    __shared__ float sval[2048];
    int n = ((const int*)ws)[WS_SCAL + 2];
    int tid = threadIdx.x;
    int nl = n < 2048 ? n : 2048;
    for (int t = tid; t < nl; t += 256) {
        sidx[t] = ((const int*)ws)[WS_IDX + t];
        sval[t] = ws[WS_VAL + t];
    }
    __syncthreads();
    int j4 = blockIdx.x * 256 + tid;  // float4 column index, 0..2047
    const f4* S4 = (const f4*)S;
    f4 acc = {0.f, 0.f, 0.f, 0.f};
    for (int t = blockIdx.y; t < n; t += 16) {
        int   ii = (t < 2048) ? sidx[t] : ((const int*)ws)[WS_IDX + t];
        float vv = (t < 2048) ? sval[t] : ws[WS_VAL + t];
        acc += vv * S4[(size_t)ii * (HD / 4) + j4];
    }
    ((f4*)(ws + WS_YPART))[blockIdx.y * (HD / 4) + j4] = acc;
}

// ---------- K4a: parallel finalize — tanh/state/out + per-block partial dots ----------
__global__ __launch_bounds__(256) void k_fin_a(const float* __restrict__ state,
                                               const float* __restrict__ Wc,
                                               float* __restrict__ ws,
                                               float* __restrict__ out) {
    int tid = threadIdx.x;
    int j = blockIdx.x * 256 + tid;  // 0..8191
    float y = 0.f;
#pragma unroll
    for (int r = 0; r < 16; ++r) y += ws[WS_YPART + r * HD + j];
    float hsj = ws[WS_HS + j];
    float ns = tanhf(y + state[j]);
    out[2 + j] = ns;
    double dy  = (double)(y * hsj);
    double sh2 = (double)(hsj * hsj);
    double l0  = (double)(ns * Wc[j]);
    double l1  = (double)(ns * Wc[HD + j]);
    __shared__ double sd[4][256];
    sd[0][tid] = dy; sd[1][tid] = sh2; sd[2][tid] = l0; sd[3][tid] = l1;
    __syncthreads();
    for (int s = 128; s; s >>= 1) {
        if (tid < s) {
            sd[0][tid] += sd[0][tid + s]; sd[1][tid] += sd[1][tid + s];
            sd[2][tid] += sd[2][tid + s]; sd[3][tid] += sd[3][tid + s];
        }
        __syncthreads();
    }
    if (tid == 0) {
        double* fp = (double*)(ws + WS_FPART);
        fp[blockIdx.x * 4 + 0] = sd[0][0];
        fp[blockIdx.x * 4 + 1] = sd[1][0];
        fp[blockIdx.x * 4 + 2] = sd[2][0];
        fp[blockIdx.x * 4 + 3] = sd[3][0];
    }
}

// ---------- K4b: combine partials -> inv_norm, logits ----------
__global__ __launch_bounds__(256) void k_fin_b(const float* __restrict__ bc,
                                               float* __restrict__ ws,
                                               float* __restrict__ out) {
    int tid = threadIdx.x;
    double ssq = 0, dy = 0, sh2 = 0, l0 = 0, l1 = 0;
    const double* sp = (const double*)(ws + WS_SSQ);
    for (int i = tid; i < 2048; i += 256) ssq += sp[i];
    const double* fp = (const double*)(ws + WS_FPART);
    if (tid < 32) {
        dy  = fp[tid * 4 + 0];
        sh2 = fp[tid * 4 + 1];
        l0  = fp[tid * 4 + 2];
        l1  = fp[tid * 4 + 3];
    }
    __shared__ double sd[5][256];
    sd[0][tid] = dy; sd[1][tid] = sh2; sd[2][tid] = l0; sd[3][tid] = l1; sd[4][tid] = ssq;
    __syncthreads();
    for (int s = 128; s; s >>= 1) {
        if (tid < s) {
            sd[0][tid] += sd[0][tid + s]; sd[1][tid] += sd[1][tid + s];
            sd[2][tid] += sd[2][tid + s]; sd[3][tid] += sd[3][tid + s];
            sd[4][tid] += sd[4][tid + s];
        }
        __syncthreads();
    }
    if (tid == 0) {
        // ||S + lr*hh^T||^2 = ||S||^2 + 2*lr*(h^T S h) + lr^2*(||h||^2)^2
        double n2 = sd[4][0] + 2.0 * (double)LR * sd[0][0]
                  + (double)LR * (double)LR * sd[1][0] * sd[1][0];
        ws[WS_SCAL + 1] = (float)(1.0 / sqrt(n2));
        out[0] = (float)(sd[2][0] + (double)bc[0]);
        out[1] = (float)(sd[3][0] + (double)bc[1]);
    }
}

// ---------- K5: new_synapses, REVERSE rows, NT stores (launched TWICE: idempotent,
// Δdur vs R12 == T_scale — decomposes the pipeline without rocprof visibility) ----------
__global__ __launch_bounds__(256) void k_scale(const float* __restrict__ S,
                                               const float* __restrict__ ws,
                                               float* __restrict__ out) {
    int row = (HD - 1) - blockIdx.x;   // reverse: MRU tail of S first -> L3 hits
    float hi  = ws[WS_HS + row] * LR;
    float inv = ws[WS_SCAL + 1];
    const f4* S4  = (const f4*)(S + (size_t)row * HD);
    const f4* hs4 = (const f4*)(ws + WS_HS);
    float* o = out + 2 + HD + (size_t)row * HD;  // offset 8194: 8B-aligned -> f2 stores
    int tid = threadIdx.x;
    if (hi != 0.f) {
#pragma unroll
        for (int it = 0; it < 8; ++it) {
            int j4 = it * 256 + tid;
            f4 s = S4[j4];
            f4 h = hs4[j4];
            f2 a  = {(s.x + hi * h.x) * inv, (s.y + hi * h.y) * inv};
            f2 bb = {(s.z + hi * h.z) * inv, (s.w + hi * h.w) * inv};
            f2* o2 = (f2*)(o + (size_t)j4 * 4);
            __builtin_nontemporal_store(a,  o2);   // no write-allocate: don't evict S
            __builtin_nontemporal_store(bb, o2 + 1);
        }
    } else {  // ~95% of rows: h_sparse[row]==0
#pragma unroll
        for (int it = 0; it < 8; ++it) {
            int j4 = it * 256 + tid;
            f4 s = S4[j4];
            f2 a  = {s.x * inv, s.y * inv};
            f2 bb = {s.z * inv, s.w * inv};
            f2* o2 = (f2*)(o + (size_t)j4 * 4);
            __builtin_nontemporal_store(a,  o2);
            __builtin_nontemporal_store(bb, o2 + 1);
        }
    }
}

extern "C" void kernel_launch(void* const* d_in, const int* in_sizes, int n_in,
                              void* d_out, int out_size, void* d_ws, size_t ws_size,
                              hipStream_t stream) {
    const float* x     = (const float*)d_in[0];
    const float* W_enc = (const float*)d_in[1];
    const float* b_enc = (const float*)d_in[2];
    const float* syn   = (const float*)d_in[3];
    const float* state = (const float*)d_in[4];
    const float* W_cls = (const float*)d_in[5];
    const float* b_cls = (const float*)d_in[6];
    float* out = (float*)d_out;
    float* ws  = (float*)d_ws;

    hipLaunchKernelGGL(k_enc,     dim3(2048),  dim3(256), 0, stream, x, W_enc, b_enc, ws);
    hipLaunchKernelGGL(k_topkssq, dim3(2049),  dim3(256), 0, stream, syn, ws);
    hipLaunchKernelGGL(k_ymv,     dim3(8, 16), dim3(256), 0, stream, syn, ws);
    hipLaunchKernelGGL(k_fin_a,   dim3(32),    dim3(256), 0, stream, state, W_cls, ws, out);
    hipLaunchKernelGGL(k_fin_b,   dim3(1),     dim3(256), 0, stream, b_cls, ws, out);
    hipLaunchKernelGGL(k_scale,   dim3(8192),  dim3(256), 0, stream, syn, ws, out);
    hipLaunchKernelGGL(k_scale,   dim3(8192),  dim3(256), 0, stream, syn, ws, out);  // diagnostic duplicate
}

// Round 16
// 190.250 us; speedup vs baseline: 1.3960x; 1.3960x over previous
//
#include <hip/hip_runtime.h>
#include <math.h>

#define HD 8192
#define ID 4096
#define KSEL 409           // int(8192 * 0.05)
#define LR 0.001f

typedef float f4 __attribute__((ext_vector_type(4)));
typedef float f2 __attribute__((ext_vector_type(2)));

// workspace layout (float indices)
#define WS_H     0                       // 8192 f32: h = relu(x@W^T + b)
#define WS_HS    8192                    // 8192 f32: h_sparse dense
#define WS_IDX   16384                   // 8192 i32: compacted nonzero indices
#define WS_VAL   24576                   // 8192 f32: compacted values
#define WS_SCAL  32768                   // [0]=kth, [1]=inv_norm, [2](int)=n
#define WS_YPART 32832                   // 16*8192 f32 partials
#define WS_SSQ   (32832 + 16*8192)       // 2048 doubles (byte off 655616, 8-aligned)
#define WS_FPART (WS_SSQ + 4096)         // 128 doubles: 32 blocks x {dy,sh2,l0,l1}
#define WS_CTR   (WS_FPART + 256)        // 1 u32: fin_a completion counter

// ---------- K1: h = relu(x @ W_enc^T + b), pure W stream ----------
__global__ __launch_bounds__(256) void k_enc(const float* __restrict__ x,
                                             const float* __restrict__ W,
                                             const float* __restrict__ b,
                                             float* __restrict__ ws) {
    __shared__ f4 sx[ID / 4];
    int tid = threadIdx.x;
    const f4* x4 = (const f4*)x;
    for (int k = tid; k < ID / 4; k += 256) sx[k] = x4[k];
    __syncthreads();
    int wave = tid >> 6, lane = tid & 63;
    int row = blockIdx.x * 4 + wave;
    const f4* w4 = (const f4*)(W + (size_t)row * ID);
    float acc = 0.f;
#pragma unroll
    for (int k = 0; k < 16; ++k) {
        f4 a  = w4[lane + 64 * k];
        f4 xv = sx[lane + 64 * k];
        acc += a.x * xv.x + a.y * xv.y + a.z * xv.z + a.w * xv.w;
    }
#pragma unroll
    for (int off = 32; off; off >>= 1) acc += __shfl_xor(acc, off, 64);
    if (lane == 0) {
        float h = acc + b[row];
        ws[WS_H + row] = h > 0.f ? h : 0.f;
    }
}

// ---------- K2 fused: blocks [0,2048) ssq(S) stream; block 2048 topk ----------
__global__ __launch_bounds__(256) void k_topkssq(const float* __restrict__ S,
                                                 float* __restrict__ ws) {
    int tid = threadIdx.x;
    if (blockIdx.x < 2048) {
        const f4* S4 = (const f4*)S;
        int gid = blockIdx.x * 256 + tid;
        double acc = 0.0;
        const int total4 = HD * HD / 4;  // 16777216
        for (int i = gid; i < total4; i += 2048 * 256) {
            f4 v = S4[i];
            acc += (double)(v.x * v.x + v.y * v.y) + (double)(v.z * v.z + v.w * v.w);
        }
        __shared__ double sd[256];
        sd[tid] = acc;
        __syncthreads();
        for (int s = 128; s; s >>= 1) {
            if (tid < s) sd[tid] += sd[tid + s];
            __syncthreads();
        }
        if (tid == 0) ((double*)(ws + WS_SSQ))[blockIdx.x] = sd[0];
        return;
    }
    // ---- block 2048: exact top-K threshold + compaction (runs in parallel) ----
    float v[32];
    const f4* h4 = (const f4*)(ws + WS_H);
#pragma unroll
    for (int k = 0; k < 8; ++k) {
        f4 t = h4[tid * 8 + k];
        v[4 * k + 0] = t.x; v[4 * k + 1] = t.y; v[4 * k + 2] = t.z; v[4 * k + 3] = t.w;
    }
    __shared__ int sred[4];
    __shared__ int wsum[4];
    // h >= 0 (relu) -> float order == uint bit order. Find largest u with
    // count(h >= u) >= K: u is exactly the Kth-largest value.
    unsigned lo = 0u, hi = 0x7F800000u;
    while (hi - lo > 1u) {
        unsigned mid = (lo + hi) >> 1;
        float t = __uint_as_float(mid);
        int c = 0;
#pragma unroll
        for (int k = 0; k < 32; ++k) c += (v[k] >= t) ? 1 : 0;
#pragma unroll
        for (int off = 32; off; off >>= 1) c += __shfl_xor(c, off, 64);
        if ((tid & 63) == 0) sred[tid >> 6] = c;
        __syncthreads();
        int cnt = sred[0] + sred[1] + sred[2] + sred[3];
        __syncthreads();
        if (cnt >= KSEL) lo = mid; else hi = mid;
    }
    float kth = __uint_as_float(lo);

    int cnt_t = 0;
    f4* hs4 = (f4*)(ws + WS_HS);
#pragma unroll
    for (int k = 0; k < 8; ++k) {
        f4 o;
        o.x = (v[4 * k + 0] >= kth) ? v[4 * k + 0] : 0.f;
        o.y = (v[4 * k + 1] >= kth) ? v[4 * k + 1] : 0.f;
        o.z = (v[4 * k + 2] >= kth) ? v[4 * k + 2] : 0.f;
        o.w = (v[4 * k + 3] >= kth) ? v[4 * k + 3] : 0.f;
        hs4[tid * 8 + k] = o;
    }
#pragma unroll
    for (int k = 0; k < 32; ++k) cnt_t += ((v[k] >= kth) && (v[k] > 0.f)) ? 1 : 0;

    int c = cnt_t;
#pragma unroll
    for (int off = 1; off < 64; off <<= 1) {
        int y = __shfl_up(c, off, 64);
        if ((tid & 63) >= off) c += y;
    }
    if ((tid & 63) == 63) wsum[tid >> 6] = c;
    __syncthreads();
    int base = 0;
    for (int w = 0; w < (tid >> 6); ++w) base += wsum[w];
    int p = base + c - cnt_t;

    int* idx = ((int*)ws) + WS_IDX;
#pragma unroll
    for (int k = 0; k < 32; ++k) {
        float val = v[k];
        if ((val >= kth) && (val > 0.f)) {
            idx[p] = tid * 32 + k;
            ws[WS_VAL + p] = val;
            ++p;
        }
    }
    if (tid == 0) {
        ws[WS_SCAL + 0] = kth;
        ((int*)ws)[WS_SCAL + 2] = wsum[0] + wsum[1] + wsum[2] + wsum[3];
    }
}

// ---------- K3: y_partial = h_sparse @ S (rows L3-hot from ssq) ----------
__global__ __launch_bounds__(256) void k_ymv(const float* __restrict__ S,
                                             float* __restrict__ ws) {
    __shared__ int   sidx[2048];
    __shared__ float sval[2048];
    int n = ((const int*)ws)[WS_SCAL + 2];
    int tid = threadIdx.x;
    int nl = n < 2048 ? n : 2048;
    for (int t = tid; t < nl; t += 256) {
        sidx[t] = ((const int*)ws)[WS_IDX + t];
        sval[t] = ws[WS_VAL + t];
    }
    __syncthreads();
    int j4 = blockIdx.x * 256 + tid;  // float4 column index, 0..2047
    const f4* S4 = (const f4*)S;
    f4 acc = {0.f, 0.f, 0.f, 0.f};
    for (int t = blockIdx.y; t < n; t += 16) {
        int   ii = (t < 2048) ? sidx[t] : ((const int*)ws)[WS_IDX + t];
        float vv = (t < 2048) ? sval[t] : ws[WS_VAL + t];
        acc += vv * S4[(size_t)ii * (HD / 4) + j4];
    }
    ((f4*)(ws + WS_YPART))[blockIdx.y * (HD / 4) + j4] = acc;
}

// ---------- K4: finalize — tanh/state/out + partials; LAST block combines ----------
__global__ __launch_bounds__(256) void k_fin(const float* __restrict__ state,
                                             const float* __restrict__ Wc,
                                             const float* __restrict__ bc,
                                             float* __restrict__ ws,
                                             float* __restrict__ out) {
    int tid = threadIdx.x;
    int j = blockIdx.x * 256 + tid;  // 0..8191
    float y = 0.f;
#pragma unroll
    for (int r = 0; r < 16; ++r) y += ws[WS_YPART + r * HD + j];
    float hsj = ws[WS_HS + j];
    float ns = tanhf(y + state[j]);
    out[2 + j] = ns;
    double dy  = (double)(y * hsj);
    double sh2 = (double)(hsj * hsj);
    double l0  = (double)(ns * Wc[j]);
    double l1  = (double)(ns * Wc[HD + j]);
    __shared__ double sd[4][256];
    sd[0][tid] = dy; sd[1][tid] = sh2; sd[2][tid] = l0; sd[3][tid] = l1;
    __syncthreads();
    for (int s = 128; s; s >>= 1) {
        if (tid < s) {
            sd[0][tid] += sd[0][tid + s]; sd[1][tid] += sd[1][tid + s];
            sd[2][tid] += sd[2][tid + s]; sd[3][tid] += sd[3][tid + s];
        }
        __syncthreads();
    }
    __shared__ int slast;
    if (tid == 0) {
        double* fp = (double*)(ws + WS_FPART);
        fp[blockIdx.x * 4 + 0] = sd[0][0];
        fp[blockIdx.x * 4 + 1] = sd[1][0];
        fp[blockIdx.x * 4 + 2] = sd[2][0];
        fp[blockIdx.x * 4 + 3] = sd[3][0];
        __threadfence();   // release: partials visible before counter bump
        unsigned prev = atomicAdd((unsigned*)ws + WS_CTR, 1u);
        slast = (prev == 31u) ? 1 : 0;
        if (slast) __threadfence();  // acquire: see all 32 blocks' partials
    }
    __syncthreads();
    if (!slast) return;

    // ---- last block: combine -> inv_norm + logits (former fin_b) ----
    double ssq = 0, dyt = 0, sh2t = 0, l0t = 0, l1t = 0;
    const double* sp = (const double*)(ws + WS_SSQ);
    for (int i = tid; i < 2048; i += 256) ssq += sp[i];
    const double* fp = (const double*)(ws + WS_FPART);
    if (tid < 32) {
        dyt  = fp[tid * 4 + 0];
        sh2t = fp[tid * 4 + 1];
        l0t  = fp[tid * 4 + 2];
        l1t  = fp[tid * 4 + 3];
    }
    __shared__ double se[5][256];
    se[0][tid] = dyt; se[1][tid] = sh2t; se[2][tid] = l0t; se[3][tid] = l1t; se[4][tid] = ssq;
    __syncthreads();
    for (int s = 128; s; s >>= 1) {
        if (tid < s) {
            se[0][tid] += se[0][tid + s]; se[1][tid] += se[1][tid + s];
            se[2][tid] += se[2][tid + s]; se[3][tid] += se[3][tid + s];
            se[4][tid] += se[4][tid + s];
        }
        __syncthreads();
    }
    if (tid == 0) {
        // ||S + lr*hh^T||^2 = ||S||^2 + 2*lr*(h^T S h) + lr^2*(||h||^2)^2
        double n2 = se[4][0] + 2.0 * (double)LR * se[0][0]
                  + (double)LR * (double)LR * se[1][0] * se[1][0];
        ws[WS_SCAL + 1] = (float)(1.0 / sqrt(n2));
        out[0] = (float)(se[2][0] + (double)bc[0]);
        out[1] = (float)(se[3][0] + (double)bc[1]);
    }
}

// ---------- K5: new_synapses, REVERSE rows, NT stores ----------
__global__ __launch_bounds__(256) void k_scale(const float* __restrict__ S,
                                               const float* __restrict__ ws,
                                               float* __restrict__ out) {
    int row = (HD - 1) - blockIdx.x;
    float hi  = ws[WS_HS + row] * LR;
    float inv = ws[WS_SCAL + 1];
    const f4* S4  = (const f4*)(S + (size_t)row * HD);
    const f4* hs4 = (const f4*)(ws + WS_HS);
    float* o = out + 2 + HD + (size_t)row * HD;  // offset 8194: 8B-aligned -> f2 stores
    int tid = threadIdx.x;
    if (hi != 0.f) {
#pragma unroll
        for (int it = 0; it < 8; ++it) {
            int j4 = it * 256 + tid;
            f4 s = S4[j4];
            f4 h = hs4[j4];
            f2 a  = {(s.x + hi * h.x) * inv, (s.y + hi * h.y) * inv};
            f2 bb = {(s.z + hi * h.z) * inv, (s.w + hi * h.w) * inv};
            f2* o2 = (f2*)(o + (size_t)j4 * 4);
            __builtin_nontemporal_store(a,  o2);   // no write-allocate
            __builtin_nontemporal_store(bb, o2 + 1);
        }
    } else {  // ~95% of rows: h_sparse[row]==0
#pragma unroll
        for (int it = 0; it < 8; ++it) {
            int j4 = it * 256 + tid;
            f4 s = S4[j4];
            f2 a  = {s.x * inv, s.y * inv};
            f2 bb = {s.z * inv, s.w * inv};
            f2* o2 = (f2*)(o + (size_t)j4 * 4);
            __builtin_nontemporal_store(a,  o2);
            __builtin_nontemporal_store(bb, o2 + 1);
        }
    }
}

extern "C" void kernel_launch(void* const* d_in, const int* in_sizes, int n_in,
                              void* d_out, int out_size, void* d_ws, size_t ws_size,
                              hipStream_t stream) {
    const float* x     = (const float*)d_in[0];
    const float* W_enc = (const float*)d_in[1];
    const float* b_enc = (const float*)d_in[2];
    const float* syn   = (const float*)d_in[3];
    const float* state = (const float*)d_in[4];
    const float* W_cls = (const float*)d_in[5];
    const float* b_cls = (const float*)d_in[6];
    float* out = (float*)d_out;
    float* ws  = (float*)d_ws;

    hipMemsetAsync((char*)d_ws + (size_t)WS_CTR * 4, 0, 4, stream);  // reset fin counter
    hipLaunchKernelGGL(k_enc,     dim3(2048),  dim3(256), 0, stream, x, W_enc, b_enc, ws);
    hipLaunchKernelGGL(k_topkssq, dim3(2049),  dim3(256), 0, stream, syn, ws);
    hipLaunchKernelGGL(k_ymv,     dim3(8, 16), dim3(256), 0, stream, syn, ws);
    hipLaunchKernelGGL(k_fin,     dim3(32),    dim3(256), 0, stream, state, W_cls, b_cls, ws, out);
    hipLaunchKernelGGL(k_scale,   dim3(8192),  dim3(256), 0, stream, syn, ws, out);
}

// Round 17
// 183.030 us; speedup vs baseline: 1.4510x; 1.0394x over previous
//
#include <hip/hip_runtime.h>
#include <math.h>

#define HD 8192
#define ID 4096
#define KSEL 409           // int(8192 * 0.05)
#define LR 0.001f

typedef float f4 __attribute__((ext_vector_type(4)));
typedef float f2 __attribute__((ext_vector_type(2)));

// workspace layout (float indices)
#define WS_H     0                       // 8192 f32: h = relu(x@W^T + b)
#define WS_HS    8192                    // 8192 f32: h_sparse dense
#define WS_IDX   16384                   // 8192 i32: compacted nonzero indices
#define WS_VAL   24576                   // 8192 f32: compacted values
#define WS_SCAL  32768                   // [0]=kth, [1]=inv_norm, [2](int)=n
#define WS_YPART 32832                   // 16*8192 f32 partials
#define WS_SSQ   (32832 + 16*8192)       // 2048 doubles (byte off 655616, 8-aligned)
#define WS_FPART (WS_SSQ + 4096)         // 128 doubles: 32 blocks x {dy,sh2,l0,l1}

// ---------- K1: h = relu(x @ W_enc^T + b), pure W stream ----------
__global__ __launch_bounds__(256) void k_enc(const float* __restrict__ x,
                                             const float* __restrict__ W,
                                             const float* __restrict__ b,
                                             float* __restrict__ ws) {
    __shared__ f4 sx[ID / 4];
    int tid = threadIdx.x;
    const f4* x4 = (const f4*)x;
    for (int k = tid; k < ID / 4; k += 256) sx[k] = x4[k];
    __syncthreads();
    int wave = tid >> 6, lane = tid & 63;
    int row = blockIdx.x * 4 + wave;
    const f4* w4 = (const f4*)(W + (size_t)row * ID);
    float acc = 0.f;
#pragma unroll
    for (int k = 0; k < 16; ++k) {
        f4 a  = w4[lane + 64 * k];
        f4 xv = sx[lane + 64 * k];
        acc += a.x * xv.x + a.y * xv.y + a.z * xv.z + a.w * xv.w;
    }
#pragma unroll
    for (int off = 32; off; off >>= 1) acc += __shfl_xor(acc, off, 64);
    if (lane == 0) {
        float h = acc + b[row];
        ws[WS_H + row] = h > 0.f ? h : 0.f;
    }
}

// ---------- K2 fused: blocks [0,2048) ssq(S) 4-deep MLP; block 2048 topk ----------
__global__ __launch_bounds__(256) void k_topkssq(const float* __restrict__ S,
                                                 float* __restrict__ ws) {
    int tid = threadIdx.x;
    if (blockIdx.x < 2048) {
        const f4* S4 = (const f4*)S;
        const int T = 2048 * 256;        // grid stride
        const int total4 = HD * HD / 4;  // 16777216 = 32*T
        int i = blockIdx.x * 256 + tid;
        double a0 = 0, a1 = 0, a2 = 0, a3 = 0;
        for (; i + 3 * T < total4; i += 4 * T) {   // 4 independent loads in flight
            f4 v0 = S4[i], v1 = S4[i + T], v2 = S4[i + 2 * T], v3 = S4[i + 3 * T];
            a0 += (double)(v0.x * v0.x + v0.y * v0.y) + (double)(v0.z * v0.z + v0.w * v0.w);
            a1 += (double)(v1.x * v1.x + v1.y * v1.y) + (double)(v1.z * v1.z + v1.w * v1.w);
            a2 += (double)(v2.x * v2.x + v2.y * v2.y) + (double)(v2.z * v2.z + v2.w * v2.w);
            a3 += (double)(v3.x * v3.x + v3.y * v3.y) + (double)(v3.z * v3.z + v3.w * v3.w);
        }
        for (; i < total4; i += T) {
            f4 v0 = S4[i];
            a0 += (double)(v0.x * v0.x + v0.y * v0.y) + (double)(v0.z * v0.z + v0.w * v0.w);
        }
        __shared__ double sd[256];
        sd[tid] = (a0 + a1) + (a2 + a3);
        __syncthreads();
        for (int s = 128; s; s >>= 1) {
            if (tid < s) sd[tid] += sd[tid + s];
            __syncthreads();
        }
        if (tid == 0) ((double*)(ws + WS_SSQ))[blockIdx.x] = sd[0];
        return;
    }
    // ---- block 2048: exact top-K threshold + compaction (runs in parallel) ----
    float v[32];
    const f4* h4 = (const f4*)(ws + WS_H);
#pragma unroll
    for (int k = 0; k < 8; ++k) {
        f4 t = h4[tid * 8 + k];
        v[4 * k + 0] = t.x; v[4 * k + 1] = t.y; v[4 * k + 2] = t.z; v[4 * k + 3] = t.w;
    }
    __shared__ int sred[4];
    __shared__ int wsum[4];
    // h >= 0 (relu) -> float order == uint bit order. Find largest u with
    // count(h >= u) >= K: u is exactly the Kth-largest value.
    unsigned lo = 0u, hi = 0x7F800000u;
    while (hi - lo > 1u) {
        unsigned mid = (lo + hi) >> 1;
        float t = __uint_as_float(mid);
        int c = 0;
#pragma unroll
        for (int k = 0; k < 32; ++k) c += (v[k] >= t) ? 1 : 0;
#pragma unroll
        for (int off = 32; off; off >>= 1) c += __shfl_xor(c, off, 64);
        if ((tid & 63) == 0) sred[tid >> 6] = c;
        __syncthreads();
        int cnt = sred[0] + sred[1] + sred[2] + sred[3];
        __syncthreads();
        if (cnt >= KSEL) lo = mid; else hi = mid;
    }
    float kth = __uint_as_float(lo);

    int cnt_t = 0;
    f4* hs4 = (f4*)(ws + WS_HS);
#pragma unroll
    for (int k = 0; k < 8; ++k) {
        f4 o;
        o.x = (v[4 * k + 0] >= kth) ? v[4 * k + 0] : 0.f;
        o.y = (v[4 * k + 1] >= kth) ? v[4 * k + 1] : 0.f;
        o.z = (v[4 * k + 2] >= kth) ? v[4 * k + 2] : 0.f;
        o.w = (v[4 * k + 3] >= kth) ? v[4 * k + 3] : 0.f;
        hs4[tid * 8 + k] = o;
    }
#pragma unroll
    for (int k = 0; k < 32; ++k) cnt_t += ((v[k] >= kth) && (v[k] > 0.f)) ? 1 : 0;

    int c = cnt_t;
#pragma unroll
    for (int off = 1; off < 64; off <<= 1) {
        int y = __shfl_up(c, off, 64);
        if ((tid & 63) >= off) c += y;
    }
    if ((tid & 63) == 63) wsum[tid >> 6] = c;
    __syncthreads();
    int base = 0;
    for (int w = 0; w < (tid >> 6); ++w) base += wsum[w];
    int p = base + c - cnt_t;

    int* idx = ((int*)ws) + WS_IDX;
#pragma unroll
    for (int k = 0; k < 32; ++k) {
        float val = v[k];
        if ((val >= kth) && (val > 0.f)) {
            idx[p] = tid * 32 + k;
            ws[WS_VAL + p] = val;
            ++p;
        }
    }
    if (tid == 0) {
        ws[WS_SCAL + 0] = kth;
        ((int*)ws)[WS_SCAL + 2] = wsum[0] + wsum[1] + wsum[2] + wsum[3];
    }
}

// ---------- K3: y_partial = h_sparse @ S (rows L3-hot from ssq) ----------
__global__ __launch_bounds__(256) void k_ymv(const float* __restrict__ S,
                                             float* __restrict__ ws) {
    __shared__ int   sidx[2048];
    __shared__ float sval[2048];
    int n = ((const int*)ws)[WS_SCAL + 2];
    int tid = threadIdx.x;
    int nl = n < 2048 ? n : 2048;
    for (int t = tid; t < nl; t += 256) {
        sidx[t] = ((const int*)ws)[WS_IDX + t];
        sval[t] = ws[WS_VAL + t];
    }
    __syncthreads();
    int j4 = blockIdx.x * 256 + tid;  // float4 column index, 0..2047
    const f4* S4 = (const f4*)S;
    f4 acc = {0.f, 0.f, 0.f, 0.f};
    for (int t = blockIdx.y; t < n; t += 16) {
        int   ii = (t < 2048) ? sidx[t] : ((const int*)ws)[WS_IDX + t];
        float vv = (t < 2048) ? sval[t] : ws[WS_VAL + t];
        acc += vv * S4[(size_t)ii * (HD / 4) + j4];
    }
    ((f4*)(ws + WS_YPART))[blockIdx.y * (HD / 4) + j4] = acc;
}

// ---------- K4a: parallel finalize — tanh/state/out + per-block partial dots ----------
__global__ __launch_bounds__(256) void k_fin_a(const float* __restrict__ state,
                                               const float* __restrict__ Wc,
                                               float* __restrict__ ws,
                                               float* __restrict__ out) {
    int tid = threadIdx.x;
    int j = blockIdx.x * 256 + tid;  // 0..8191
    float y = 0.f;
#pragma unroll
    for (int r = 0; r < 16; ++r) y += ws[WS_YPART + r * HD + j];
    float hsj = ws[WS_HS + j];
    float ns = tanhf(y + state[j]);
    out[2 + j] = ns;
    double dy  = (double)(y * hsj);
    double sh2 = (double)(hsj * hsj);
    double l0  = (double)(ns * Wc[j]);
    double l1  = (double)(ns * Wc[HD + j]);
    __shared__ double sd[4][256];
    sd[0][tid] = dy; sd[1][tid] = sh2; sd[2][tid] = l0; sd[3][tid] = l1;
    __syncthreads();
    for (int s = 128; s; s >>= 1) {
        if (tid < s) {
            sd[0][tid] += sd[0][tid + s]; sd[1][tid] += sd[1][tid + s];
            sd[2][tid] += sd[2][tid + s]; sd[3][tid] += sd[3][tid + s];
        }
        __syncthreads();
    }
    if (tid == 0) {
        double* fp = (double*)(ws + WS_FPART);
        fp[blockIdx.x * 4 + 0] = sd[0][0];
        fp[blockIdx.x * 4 + 1] = sd[1][0];
        fp[blockIdx.x * 4 + 2] = sd[2][0];
        fp[blockIdx.x * 4 + 3] = sd[3][0];
    }
}

// ---------- K4b: combine partials -> inv_norm, logits ----------
__global__ __launch_bounds__(256) void k_fin_b(const float* __restrict__ bc,
                                               float* __restrict__ ws,
                                               float* __restrict__ out) {
    int tid = threadIdx.x;
    double ssq = 0, dy = 0, sh2 = 0, l0 = 0, l1 = 0;
    const double* sp = (const double*)(ws + WS_SSQ);
    for (int i = tid; i < 2048; i += 256) ssq += sp[i];
    const double* fp = (const double*)(ws + WS_FPART);
    if (tid < 32) {
        dy  = fp[tid * 4 + 0];
        sh2 = fp[tid * 4 + 1];
        l0  = fp[tid * 4 + 2];
        l1  = fp[tid * 4 + 3];
    }
    __shared__ double sd[5][256];
    sd[0][tid] = dy; sd[1][tid] = sh2; sd[2][tid] = l0; sd[3][tid] = l1; sd[4][tid] = ssq;
    __syncthreads();
    for (int s = 128; s; s >>= 1) {
        if (tid < s) {
            sd[0][tid] += sd[0][tid + s]; sd[1][tid] += sd[1][tid + s];
            sd[2][tid] += sd[2][tid + s]; sd[3][tid] += sd[3][tid + s];
            sd[4][tid] += sd[4][tid + s];
        }
        __syncthreads();
    }
    if (tid == 0) {
        // ||S + lr*hh^T||^2 = ||S||^2 + 2*lr*(h^T S h) + lr^2*(||h||^2)^2
        double n2 = sd[4][0] + 2.0 * (double)LR * sd[0][0]
                  + (double)LR * (double)LR * sd[1][0] * sd[1][0];
        ws[WS_SCAL + 1] = (float)(1.0 / sqrt(n2));
        out[0] = (float)(sd[2][0] + (double)bc[0]);
        out[1] = (float)(sd[3][0] + (double)bc[1]);
    }
}

// ---------- K5: new_synapses, 2 rows/block interleaved, NT stores ----------
__global__ __launch_bounds__(256) void k_scale(const float* __restrict__ S,
                                               const float* __restrict__ ws,
                                               float* __restrict__ out) {
    int rb = 4095 - blockIdx.x;        // reverse pairs (harmless; scale is HBM-bound)
    int row0 = rb * 2, row1 = rb * 2 + 1;
    float hi0 = ws[WS_HS + row0] * LR;
    float hi1 = ws[WS_HS + row1] * LR;
    float inv = ws[WS_SCAL + 1];
    const f4* A = (const f4*)(S + (size_t)row0 * HD);
    const f4* B = (const f4*)(S + (size_t)row1 * HD);
    const f4* hs4 = (const f4*)(ws + WS_HS);
    float* oa = out + 2 + HD + (size_t)row0 * HD;  // 8B-aligned -> f2 stores
    float* ob = out + 2 + HD + (size_t)row1 * HD;
    int tid = threadIdx.x;
#pragma unroll
    for (int it = 0; it < 8; ++it) {
        int j4 = it * 256 + tid;
        f4 sa = A[j4];                 // two independent row streams in flight
        f4 sb = B[j4];
        f4 h  = hs4[j4];               // one hs load serves both rows
        f2 a0 = {(sa.x + hi0 * h.x) * inv, (sa.y + hi0 * h.y) * inv};
        f2 a1 = {(sa.z + hi0 * h.z) * inv, (sa.w + hi0 * h.w) * inv};
        f2 b0 = {(sb.x + hi1 * h.x) * inv, (sb.y + hi1 * h.y) * inv};
        f2 b1 = {(sb.z + hi1 * h.z) * inv, (sb.w + hi1 * h.w) * inv};
        f2* oa2 = (f2*)(oa + (size_t)j4 * 4);
        f2* ob2 = (f2*)(ob + (size_t)j4 * 4);
        __builtin_nontemporal_store(a0, oa2);      // no write-allocate
        __builtin_nontemporal_store(a1, oa2 + 1);
        __builtin_nontemporal_store(b0, ob2);
        __builtin_nontemporal_store(b1, ob2 + 1);
    }
}

extern "C" void kernel_launch(void* const* d_in, const int* in_sizes, int n_in,
                              void* d_out, int out_size, void* d_ws, size_t ws_size,
                              hipStream_t stream) {
    const float* x     = (const float*)d_in[0];
    const float* W_enc = (const float*)d_in[1];
    const float* b_enc = (const float*)d_in[2];
    const float* syn   = (const float*)d_in[3];
    const float* state = (const float*)d_in[4];
    const float* W_cls = (const float*)d_in[5];
    const float* b_cls = (const float*)d_in[6];
    float* out = (float*)d_out;
    float* ws  = (float*)d_ws;

    hipLaunchKernelGGL(k_enc,     dim3(2048),  dim3(256), 0, stream, x, W_enc, b_enc, ws);
    hipLaunchKernelGGL(k_topkssq, dim3(2049),  dim3(256), 0, stream, syn, ws);
    hipLaunchKernelGGL(k_ymv,     dim3(8, 16), dim3(256), 0, stream, syn, ws);
    hipLaunchKernelGGL(k_fin_a,   dim3(32),    dim3(256), 0, stream, state, W_cls, ws, out);
    hipLaunchKernelGGL(k_fin_b,   dim3(1),     dim3(256), 0, stream, b_cls, ws, out);
    hipLaunchKernelGGL(k_scale,   dim3(4096),  dim3(256), 0, stream, syn, ws, out);
}